// Round 3
// baseline (583.846 us; speedup 1.0000x reference)
//
#include <hip/hip_runtime.h>
#include <math.h>

typedef short bf16x8 __attribute__((ext_vector_type(8)));
typedef float f32x4 __attribute__((ext_vector_type(4)));
typedef unsigned short ushort8 __attribute__((ext_vector_type(8)));

constexpr int R = 128, Cc = 256, E = 768, H = 12;
constexpr int M = R * Cc;                 // 32768 tokens
constexpr size_t TOK = (size_t)M * E;     // 25165824

__device__ __forceinline__ unsigned short f2b(float f) {
  unsigned int u = __float_as_uint(f);
  u += 0x7fff + ((u >> 16) & 1);
  return (unsigned short)(u >> 16);
}

__device__ __forceinline__ void ldst16(const unsigned short* g, unsigned short* l) {
  __builtin_amdgcn_global_load_lds(
      (const __attribute__((address_space(1))) unsigned int*)g,
      (__attribute__((address_space(3))) unsigned int*)l, 16, 0, 0);
}

__global__ __launch_bounds__(256) void cvt_bf16(const float* __restrict__ in,
                                                unsigned short* __restrict__ out,
                                                int n8) {
  int i = blockIdx.x * 256 + threadIdx.x;
  if (i >= n8) return;
  const float4* p = (const float4*)in;
  float4 a = p[2 * i], b = p[2 * i + 1];
  ushort8 o;
  o[0] = f2b(a.x); o[1] = f2b(a.y); o[2] = f2b(a.z); o[3] = f2b(a.w);
  o[4] = f2b(b.x); o[5] = f2b(b.y); o[6] = f2b(b.z); o[7] = f2b(b.w);
  ((ushort8*)out)[i] = o;
}

// ---------------------------------------------------------------------------
// Shared GEMM core: 128x128 tile, BK=64, 256 thr, 4 waves 2x2 (64x64 each).
// Per K-iter: stage 16KB+16KB via global_load_lds(16B), 32 MFMA/wave.
// As/Bs are [128][64] bf16 row-major (exactly the ldst16 landing order).
// ---------------------------------------------------------------------------
template <int KITERS>
__device__ __forceinline__ void gemm_core(
    const unsigned short* __restrict__ Aptr, size_t Astride,
    const unsigned short* __restrict__ Bptr, size_t Bstride,
    unsigned short* As, unsigned short* Bs, int wv, int ln, f32x4 acc[4][4]) {
  const int srow = ln >> 3, scol = (ln & 7) * 8;   // 8 lanes x 16B per 128B row
  const int wm = (wv & 1) * 64, wn = (wv >> 1) * 64;
#pragma unroll 1
  for (int kt = 0; kt < KITERS; ++kt) {
    const int k0 = kt * 64;
    __syncthreads();
#pragma unroll
    for (int t = 0; t < 4; ++t) {
      const int ch = wv * 4 + t;                   // 16 chunks of 8 rows
      const int row = ch * 8 + srow;
      ldst16(Aptr + (size_t)row * Astride + k0 + scol, As + ch * 512 + ln * 8);
      ldst16(Bptr + (size_t)row * Bstride + k0 + scol, Bs + ch * 512 + ln * 8);
    }
    __syncthreads();
#pragma unroll
    for (int dk = 0; dk < 2; ++dk) {
      bf16x8 a[4], b[4];
#pragma unroll
      for (int i = 0; i < 4; ++i)
        a[i] = *(const bf16x8*)(As + (wm + i * 16 + (ln & 15)) * 64 + dk * 32 + (ln >> 4) * 8);
#pragma unroll
      for (int j = 0; j < 4; ++j)
        b[j] = *(const bf16x8*)(Bs + (wn + j * 16 + (ln & 15)) * 64 + dk * 32 + (ln >> 4) * 8);
#pragma unroll
      for (int i = 0; i < 4; ++i)
#pragma unroll
        for (int j = 0; j < 4; ++j)
          acc[i][j] = __builtin_amdgcn_mfma_f32_16x16x32_bf16(a[i], b[j], acc[i][j], 0, 0, 0);
    }
  }
}

// ---------------------------------------------------------------------------
// Fused QKV: A=x_bf[M][768], B=Wqkv_bf[2304][768].  Epilogue scatters:
//  q -> q'[h][i][r*64+d] (*scale, +bq)   k -> k'[h][j][r*64+d] (+bk)
//  v -> v''[h][r*64+d][j] (+bv)
// ---------------------------------------------------------------------------
__global__ __launch_bounds__(256) void qkv_mfma(
    const unsigned short* __restrict__ A, const unsigned short* __restrict__ B,
    const float* __restrict__ bq, const float* __restrict__ bk,
    const float* __restrict__ bv, unsigned short* __restrict__ qp,
    unsigned short* __restrict__ kp, unsigned short* __restrict__ vp, float scale) {
  __shared__ unsigned short As[128 * 64];
  __shared__ unsigned short Bs[128 * 64];
  const int tid = threadIdx.x, wv = tid >> 6, ln = tid & 63;
  const int n0 = blockIdx.x * 128, m0 = blockIdx.y * 128;
  const int wm = (wv & 1) * 64, wn = (wv >> 1) * 64;
  f32x4 acc[4][4] = {};
  gemm_core<12>(A + (size_t)m0 * E, E, B + (size_t)n0 * E, E, As, Bs, wv, ln, acc);
  const int part = n0 / 768;  // block-uniform: 0=q 1=k 2=v
  const float* bias = part == 0 ? bq : (part == 1 ? bk : bv);
  const float sc = part == 0 ? scale : 1.0f;
#pragma unroll
  for (int j = 0; j < 4; ++j) {
    const int n = n0 + wn + j * 16 + (ln & 15);
    const int nn = n - part * 768;
    const int h = nn >> 6, d = nn & 63;
    const float bn = bias[nn];
#pragma unroll
    for (int i = 0; i < 4; ++i)
#pragma unroll
      for (int r4 = 0; r4 < 4; ++r4) {
        const int m = m0 + wm + i * 16 + (ln >> 4) * 4 + r4;
        const int r = m >> 8, ii = m & 255;
        const unsigned short val = f2b((acc[i][j][r4] + bn) * sc);
        if (part == 0)
          qp[((size_t)(h * 256 + ii) << 13) + r * 64 + d] = val;
        else if (part == 1)
          kp[((size_t)(h * 256 + ii) << 13) + r * 64 + d] = val;
        else
          vp[((size_t)(h * 8192 + r * 64 + d) << 8) + ii] = val;
      }
  }
}

// ---------------------------------------------------------------------------
// QK: per head M=N=256, K=8192 (r,d), split-K=8.  Partials fp32.
// ---------------------------------------------------------------------------
__global__ __launch_bounds__(256) void qk_mfma(const unsigned short* __restrict__ qp,
                                               const unsigned short* __restrict__ kp,
                                               float* __restrict__ Sp) {
  __shared__ unsigned short As[128 * 64];
  __shared__ unsigned short Bs[128 * 64];
  const int tid = threadIdx.x, wv = tid >> 6, ln = tid & 63;
  const int m0 = (blockIdx.x & 1) * 128, n0 = (blockIdx.x >> 1) * 128;
  const int h = blockIdx.y, kc = blockIdx.z;
  const int wm = (wv & 1) * 64, wn = (wv >> 1) * 64;
  f32x4 acc[4][4] = {};
  const size_t hb = (size_t)h * 256 * 8192 + kc * 1024;
  gemm_core<16>(qp + hb + (size_t)m0 * 8192, 8192,
                kp + hb + (size_t)n0 * 8192, 8192, As, Bs, wv, ln, acc);
  float* out = Sp + ((size_t)kc * H + h) * Cc * Cc;
#pragma unroll
  for (int i = 0; i < 4; ++i)
#pragma unroll
    for (int j = 0; j < 4; ++j)
#pragma unroll
      for (int r4 = 0; r4 < 4; ++r4) {
        const int mm = m0 + wm + i * 16 + (ln >> 4) * 4 + r4;
        const int nn = n0 + wn + j * 16 + (ln & 15);
        out[(size_t)mm * Cc + nn] = acc[i][j][r4];
      }
}

// ---------------------------------------------------------------------------
__global__ __launch_bounds__(256) void softmax_k(const float* __restrict__ Sp,
                                                 float* __restrict__ P,
                                                 unsigned short* __restrict__ Pb) {
  const int row = blockIdx.x, j = threadIdx.x;  // row = h*C + i
  const size_t stride = (size_t)H * Cc * Cc;
  const size_t base = (size_t)row * Cc + j;
  float s = 0.f;
#pragma unroll
  for (int kc = 0; kc < 8; ++kc) s += Sp[base + kc * stride];
  float m = s;
#pragma unroll
  for (int o = 32; o > 0; o >>= 1) m = fmaxf(m, __shfl_xor(m, o));
  __shared__ float sm[4], ss[4];
  const int wid = j >> 6, lane = j & 63;
  if (lane == 0) sm[wid] = m;
  __syncthreads();
  m = fmaxf(fmaxf(sm[0], sm[1]), fmaxf(sm[2], sm[3]));
  float e = expf(s - m);
  float t = e;
#pragma unroll
  for (int o = 32; o > 0; o >>= 1) t += __shfl_xor(t, o);
  if (lane == 0) ss[wid] = t;
  __syncthreads();
  t = ss[0] + ss[1] + ss[2] + ss[3];
  const float p = e / t;
  P[base] = p;
  Pb[base] = f2b(p);
}

// ---------------------------------------------------------------------------
// PV: per head M=256(i), N=8192(r*64+d), K=256(j).  A=P_bf[h], B=v''[h].
// Epilogue writes c in token layout [r*256+i][h*64+d] (bf16).
// ---------------------------------------------------------------------------
__global__ __launch_bounds__(256) void pv_mfma(const unsigned short* __restrict__ P,
                                               const unsigned short* __restrict__ V,
                                               unsigned short* __restrict__ Co) {
  __shared__ unsigned short As[128 * 64];
  __shared__ unsigned short Bs[128 * 64];
  const int tid = threadIdx.x, wv = tid >> 6, ln = tid & 63;
  const int m0 = (blockIdx.x & 1) * 128, n0 = (blockIdx.x >> 1) * 128;
  const int h = blockIdx.y;
  const int wm = (wv & 1) * 64, wn = (wv >> 1) * 64;
  f32x4 acc[4][4] = {};
  gemm_core<4>(P + (size_t)h * 65536 + (size_t)m0 * 256, 256,
               V + ((size_t)h * 8192 + n0) * 256, 256, As, Bs, wv, ln, acc);
#pragma unroll
  for (int j = 0; j < 4; ++j) {
    const int n = n0 + wn + j * 16 + (ln & 15);
    const int r = n >> 6, d = n & 63;
#pragma unroll
    for (int i = 0; i < 4; ++i)
#pragma unroll
      for (int r4 = 0; r4 < 4; ++r4) {
        const int ii = m0 + wm + i * 16 + (ln >> 4) * 4 + r4;
        Co[((size_t)(r * 256 + ii)) * E + h * 64 + d] = f2b(acc[i][j][r4]);
      }
  }
}

// ---------------------------------------------------------------------------
// Output proj: A=c_bf[M][768], B=Wo_bf[768][768], out fp32 + bias.
// ---------------------------------------------------------------------------
__global__ __launch_bounds__(256) void out_mfma(const unsigned short* __restrict__ A,
                                                const unsigned short* __restrict__ B,
                                                const float* __restrict__ bias,
                                                float* __restrict__ Y) {
  __shared__ unsigned short As[128 * 64];
  __shared__ unsigned short Bs[128 * 64];
  const int tid = threadIdx.x, wv = tid >> 6, ln = tid & 63;
  const int n0 = blockIdx.x * 128, m0 = blockIdx.y * 128;
  const int wm = (wv & 1) * 64, wn = (wv >> 1) * 64;
  f32x4 acc[4][4] = {};
  gemm_core<12>(A + (size_t)m0 * E, E, B + (size_t)n0 * E, E, As, Bs, wv, ln, acc);
#pragma unroll
  for (int j = 0; j < 4; ++j) {
    const int n = n0 + wn + j * 16 + (ln & 15);
    const float bn = bias[n];
#pragma unroll
    for (int i = 0; i < 4; ++i)
#pragma unroll
      for (int r4 = 0; r4 < 4; ++r4) {
        const int m = m0 + wm + i * 16 + (ln >> 4) * 4 + r4;
        Y[(size_t)m * E + n] = acc[i][j][r4] + bn;
      }
  }
}

// ---------------------------------------------------------------------------
extern "C" void kernel_launch(void* const* d_in, const int* in_sizes, int n_in,
                              void* d_out, int out_size, void* d_ws, size_t ws_size,
                              hipStream_t stream) {
  const float* x  = (const float*)d_in[0];
  const float* Wq = (const float*)d_in[1];
  const float* bq = (const float*)d_in[2];
  const float* Wk = (const float*)d_in[3];
  const float* bk = (const float*)d_in[4];
  const float* Wv = (const float*)d_in[5];
  const float* bv = (const float*)d_in[6];
  const float* Wo = (const float*)d_in[7];
  const float* bo = (const float*)d_in[8];
  float* out = (float*)d_out;             // (R,C,1,E)
  float* probs = out + TOK;               // (H,1,C,C)

  char* ws = (char*)d_ws;
  unsigned short* x_bf   = (unsigned short*)(ws);              // 50.3 MB
  unsigned short* qp     = (unsigned short*)(ws + 50331648);   // 50.3 MB [h][i][r*64+d]
  unsigned short* kp     = (unsigned short*)(ws + 100663296);  // 50.3 MB
  unsigned short* vp     = (unsigned short*)(ws + 150994944);  // 50.3 MB [h][r*64+d][j]
  unsigned short* Wqkv   = (unsigned short*)(ws + 201326592);  // 3.54 MB [2304][768]
  unsigned short* Wo_bf  = (unsigned short*)(ws + 204865536);  // 1.18 MB
  float* S_part          = (float*)(ws + 206045184);           // 25.2 MB (8 partials)
  unsigned short* P_bf   = (unsigned short*)(ws + 231211008);  // 1.57 MB
  unsigned short* c_bf   = (unsigned short*)(ws + 232783872);  // 50.3 MB

  const float scaling = 0.125f / sqrtf(128.f);  // Dk^-0.5 / sqrt(R)

  cvt_bf16<<<12288, 256, 0, stream>>>(x, x_bf, 3145728);
  cvt_bf16<<<288, 256, 0, stream>>>(Wq, Wqkv, 73728);
  cvt_bf16<<<288, 256, 0, stream>>>(Wk, Wqkv + 589824, 73728);
  cvt_bf16<<<288, 256, 0, stream>>>(Wv, Wqkv + 1179648, 73728);
  cvt_bf16<<<288, 256, 0, stream>>>(Wo, Wo_bf, 73728);

  qkv_mfma<<<dim3(18, 256), 256, 0, stream>>>(x_bf, Wqkv, bq, bk, bv, qp, kp, vp, scaling);
  qk_mfma<<<dim3(4, H, 8), 256, 0, stream>>>(qp, kp, S_part);
  softmax_k<<<H * Cc, 256, 0, stream>>>(S_part, probs, P_bf);
  pv_mfma<<<dim3(128, H), 256, 0, stream>>>(P_bf, vp, c_bf);
  out_mfma<<<dim3(6, 256), 256, 0, stream>>>(c_bf, Wo_bf, bo, out);
}